// Round 1
// baseline (37973.615 us; speedup 1.0000x reference)
//
#include <hip/hip_runtime.h>
#include <hip/hip_bf16.h>
#include <cstdint>

// ---------------- problem constants ----------------
#define SEQ   512
#define BATCH 64
#define HID   512

typedef _Float16 f16x8 __attribute__((ext_vector_type(8)));
typedef float    f32x4 __attribute__((ext_vector_type(4)));

// ---------------- ws layout (bytes) ----------------
// counters: 2 pools * 512 t * 6 phases * 4B = 24576
#define WS_CNT   0
#define WS_H32   24576            // 2 pools * 64*512*4 = 262144
#define WS_H16   286720           // 2 pools * 2 bufs * 64*512*2 = 262144
#define ZERO_PREFIX 548864        // cnt + h32 + h16 zeroed each launch
#define WS_X16   548864           // 2 pools * 64*512*2 = 131072
#define WS_RING  679936           // 4 * 64*512*4 = 524288 (h1 ring, A->B)
#define WS_WT    1204224          // 2 layers * 3407872 elems * 2B = 13631488
#define WS_BS    14835712         // 2 * 2048 * 4 = 16384 (reordered bih+bhh)

#define MOG_ELEMS   (5*512*512)       // 1310720
#define GATE_ELEMS  (2048*512)        // 1048576
#define LAYER_ELEMS (MOG_ELEMS + 2*GATE_ELEMS)   // 3407872

// d_out layout (floats)
#define OUT_H 16777216            // last_hidden [2,64,512]
#define OUT_C 16842752            // last_cell   [2,64,512]

// Reordered gate layout: rg = 64*b + 16*gate + j  <->  orig row = gate*512 + 16*b + j
// so each WG w owns gate cols [64w,64w+64) = all four gates (i,f,g,o) for h-cols [16w,16w+16).
__device__ __forceinline__ int gate_orig_row(int rg) {
    return ((rg >> 4) & 3) * 512 + ((rg >> 6) << 4) + (rg & 15);
}

// ---------------- prologue: f32 -> f16 weight conversion + gate reorder ----------------
__global__ __launch_bounds__(256)
void prologue_convert(const float* __restrict__ l1_mogW, const float* __restrict__ l1_Wih,
                      const float* __restrict__ l1_Whh,  const float* __restrict__ l1_bih,
                      const float* __restrict__ l1_bhh,
                      const float* __restrict__ l2_mogW, const float* __restrict__ l2_Wih,
                      const float* __restrict__ l2_Whh,  const float* __restrict__ l2_bih,
                      const float* __restrict__ l2_bhh,  char* __restrict__ ws)
{
    _Float16* wdst = (_Float16*)(ws + WS_WT);
    const int total = 2 * LAYER_ELEMS;
    const int stride = gridDim.x * blockDim.x;
    for (int idx = blockIdx.x * blockDim.x + threadIdx.x; idx < total; idx += stride) {
        const int layer = idx >= LAYER_ELEMS;
        const int r = idx - layer * LAYER_ELEMS;
        float v;
        if (r < MOG_ELEMS) {
            v = (layer ? l2_mogW : l1_mogW)[r];
        } else {
            const int q = r - MOG_ELEMS;
            const int mat = q >= GATE_ELEMS;         // 0 = Wih, 1 = Whh
            const int e = q - mat * GATE_ELEMS;
            const int rg = e >> 9;                    // / 512
            const int k  = e & 511;
            const int orig = gate_orig_row(rg);
            const float* W = mat ? (layer ? l2_Whh : l1_Whh)
                                 : (layer ? l2_Wih : l1_Wih);
            v = W[orig * 512 + k];
        }
        wdst[idx] = (_Float16)v;
    }
    float* bs = (float*)(ws + WS_BS);
    for (int idx = blockIdx.x * blockDim.x + threadIdx.x; idx < 2 * 2048; idx += stride) {
        const int layer = idx >> 11;
        const int rg = idx & 2047;
        const int orig = gate_orig_row(rg);
        bs[idx] = (layer ? l2_bih : l1_bih)[orig] + (layer ? l2_bhh : l1_bhh)[orig];
    }
}

// ---------------- sync primitives (cross-XCD safe) ----------------
__device__ __forceinline__ void wg_wait(const unsigned* c, unsigned target) {
    if (threadIdx.x == 0) {
        while (__hip_atomic_load(c, __ATOMIC_ACQUIRE, __HIP_MEMORY_SCOPE_AGENT) < target) {
            __builtin_amdgcn_s_sleep(1);
        }
    }
    __syncthreads();   // releases WG after tid0's acquire (L1/L2 invalidate) completed
}
__device__ __forceinline__ void wg_signal(unsigned* c) {
    __syncthreads();   // all waves' stores drained to L2 (vmcnt(0) before s_barrier)
    if (threadIdx.x == 0) {
        __threadfence(); // agent fence: L2 writeback to coherence point
        __hip_atomic_fetch_add(c, 1u, __ATOMIC_RELEASE, __HIP_MEMORY_SCOPE_AGENT);
    }
}

__device__ __forceinline__ float sigf(float z) { return 1.f / (1.f + __expf(-z)); }

// ---------------- persistent kernel ----------------
// grid = 64 blocks x 256 threads. Pool 0 (blocks 0..31) = layer 1, pool 1 = layer 2.
// Each pool: 32 WGs, per-phase dataflow counters. MFMA 16x16x32 f16:
//   A-frag: row = lane&15, k = (lane>>4)*8 + j ; B-frag: col = lane&15, same k
//   C/D:    col = lane&15, row = (lane>>4)*4 + reg   [HW-verified layout]
__global__ __launch_bounds__(256, 1)
void moglstm_persist(const float* __restrict__ in_seq,
                     const float* __restrict__ mogb1,
                     const float* __restrict__ mogb2,
                     float* __restrict__ out, char* __restrict__ ws)
{
    const int pool = blockIdx.x >> 5;
    const int w    = blockIdx.x & 31;
    const int tid  = threadIdx.x;
    const int lane = tid & 63;
    const int wv   = tid >> 6;

    unsigned* cnt  = (unsigned*)(ws + WS_CNT);
    unsigned* cntA = cnt;
    unsigned* cntB = cnt + SEQ * 6;
    unsigned* cntP = cnt + pool * SEQ * 6;

    float*     h32  = (float*)(ws + WS_H32) + pool * (BATCH * HID);
    _Float16*  h16v = (_Float16*)(ws + WS_H16) + pool * (2 * BATCH * HID);
    _Float16*  x16v = (_Float16*)(ws + WS_X16) + pool * (BATCH * HID);
    float*     ring = (float*)(ws + WS_RING);
    const _Float16* Wbase = (const _Float16*)(ws + WS_WT) + pool * LAYER_ELEMS;
    const _Float16* mogW  = Wbase;
    const _Float16* wihR  = Wbase + MOG_ELEMS;
    const _Float16* whhR  = wihR + GATE_ELEMS;
    const float* mogb = pool ? mogb2 : mogb1;
    const float* bsum = (const float*)(ws + WS_BS) + pool * 2048;

    // fragment / epilogue coordinates
    const int arow  = 16 * wv + (lane & 15);      // A row (m)
    const int kof   = (lane >> 4) * 8;            // k sub-offset
    const int bcolM = 16 * w + (lane & 15);       // mog B col (n)
    const int erow0 = 16 * wv + (lane >> 4) * 4;  // C/D row base
    const int ecol  = 16 * w + (lane & 15);       // C/D col
    // gates pointwise coordinates (fixed thread<->cell ownership for c-state)
    const int prow0 = 4 * (tid >> 4);
    const int pj    = tid & 15;
    const int pcol  = 16 * w + pj;

    float xreg[4];                                // x master (f32, register)
    float creg[4] = {0.f, 0.f, 0.f, 0.f};         // c master (f32, register)

    __shared__ float lds[BATCH * 64];             // gate redistribution (16KB)

    for (int t = 0; t < SEQ; ++t) {
        _Float16* hb = h16v + (t & 1) * (BATCH * HID);        // h read by all matmuls at t
        _Float16* ho = h16v + ((t & 1) ^ 1) * (BATCH * HID);  // gates writes next-step h here

        // ---------------- mogrifier phases 0..4 ----------------
        for (int p = 0; p < 5; ++p) {
            if (p == 0) {
                if (t > 0) wg_wait(&cntP[(t - 1) * 6 + 5], 32);   // own gates(t-1)
                if (pool == 1) wg_wait(&cntA[t * 6 + 5], 32);     // h1[t] ready in ring
            } else {
                wg_wait(&cntP[t * 6 + p - 1], 32);
            }

            // p even: x = 2*sig(h @ W^T + b) * x  (matmul input h)
            // p odd : h = 2*sig(x @ W^T + b) * h  (matmul input x)
            const _Float16* act = (p & 1) ? x16v : hb;
            const _Float16* Wp  = mogW + p * (512 * 512);
            f32x4 acc = {0.f, 0.f, 0.f, 0.f};
            {
                const _Float16* ap = act + arow * 512 + kof;
                const _Float16* bp = Wp + bcolM * 512 + kof;
                #pragma unroll
                for (int ks = 0; ks < 16; ++ks) {
                    f16x8 a = *(const f16x8*)(ap + ks * 32);
                    f16x8 b = *(const f16x8*)(bp + ks * 32);
                    acc = __builtin_amdgcn_mfma_f32_16x16x32_f16(a, b, acc, 0, 0, 0);
                }
            }
            #pragma unroll
            for (int r = 0; r < 4; ++r) {
                const int row = erow0 + r;
                const float g = acc[r] + mogb[p * 512 + ecol];
                const float s = 2.f * sigf(g);
                if ((p & 1) == 0) {
                    float xo;
                    if (p == 0) {
                        xo = (pool == 0) ? in_seq[t * (BATCH * HID) + row * HID + ecol]
                                         : ring[(t & 3) * (BATCH * HID) + row * HID + ecol];
                    } else {
                        xo = xreg[r];
                    }
                    const float xn = s * xo;
                    xreg[r] = xn;
                    x16v[row * HID + ecol] = (_Float16)xn;
                } else {
                    const float hn = s * h32[row * HID + ecol];
                    h32[row * HID + ecol] = hn;
                    hb[row * HID + ecol] = (_Float16)hn;
                }
            }
            wg_signal(&cntP[t * 6 + p]);
        }

        // ---------------- LSTM gates ----------------
        wg_wait(&cntP[t * 6 + 4], 32);
        if (pool == 0 && t >= 4) wg_wait(&cntB[(t - 4) * 6 + 0], 32);  // ring slot free

        f32x4 g0 = {0,0,0,0}, g1 = {0,0,0,0}, g2 = {0,0,0,0}, g3 = {0,0,0,0};
        {
            const _Float16* xa = x16v + arow * 512 + kof;
            const _Float16* ha = hb   + arow * 512 + kof;
            const int n0 = 64 * w + (lane & 15);
            const _Float16* bi0 = wihR + (n0     ) * 512 + kof;
            const _Float16* bi1 = wihR + (n0 + 16) * 512 + kof;
            const _Float16* bi2 = wihR + (n0 + 32) * 512 + kof;
            const _Float16* bi3 = wihR + (n0 + 48) * 512 + kof;
            const _Float16* bh0 = whhR + (n0     ) * 512 + kof;
            const _Float16* bh1 = whhR + (n0 + 16) * 512 + kof;
            const _Float16* bh2 = whhR + (n0 + 32) * 512 + kof;
            const _Float16* bh3 = whhR + (n0 + 48) * 512 + kof;
            #pragma unroll
            for (int ks = 0; ks < 16; ++ks) {
                const int o = ks * 32;
                f16x8 ax = *(const f16x8*)(xa + o);
                f16x8 ah = *(const f16x8*)(ha + o);
                g0 = __builtin_amdgcn_mfma_f32_16x16x32_f16(ax, *(const f16x8*)(bi0 + o), g0, 0, 0, 0);
                g0 = __builtin_amdgcn_mfma_f32_16x16x32_f16(ah, *(const f16x8*)(bh0 + o), g0, 0, 0, 0);
                g1 = __builtin_amdgcn_mfma_f32_16x16x32_f16(ax, *(const f16x8*)(bi1 + o), g1, 0, 0, 0);
                g1 = __builtin_amdgcn_mfma_f32_16x16x32_f16(ah, *(const f16x8*)(bh1 + o), g1, 0, 0, 0);
                g2 = __builtin_amdgcn_mfma_f32_16x16x32_f16(ax, *(const f16x8*)(bi2 + o), g2, 0, 0, 0);
                g2 = __builtin_amdgcn_mfma_f32_16x16x32_f16(ah, *(const f16x8*)(bh2 + o), g2, 0, 0, 0);
                g3 = __builtin_amdgcn_mfma_f32_16x16x32_f16(ax, *(const f16x8*)(bi3 + o), g3, 0, 0, 0);
                g3 = __builtin_amdgcn_mfma_f32_16x16x32_f16(ah, *(const f16x8*)(bh3 + o), g3, 0, 0, 0);
            }
        }
        // stash raw pre-activations (+bias) in LDS, then redistribute so each thread
        // owns (row, h-col) with all four gates
        {
            const int c16 = lane & 15;
            #pragma unroll
            for (int r = 0; r < 4; ++r) {
                const int row = erow0 + r;
                lds[row * 64 + c16     ] = g0[r] + bsum[64 * w + c16     ];
                lds[row * 64 + c16 + 16] = g1[r] + bsum[64 * w + c16 + 16];
                lds[row * 64 + c16 + 32] = g2[r] + bsum[64 * w + c16 + 32];
                lds[row * 64 + c16 + 48] = g3[r] + bsum[64 * w + c16 + 48];
            }
        }
        __syncthreads();
        #pragma unroll
        for (int r = 0; r < 4; ++r) {
            const int row = prow0 + r;
            const float ig = sigf(lds[row * 64 + pj]);
            const float fg = sigf(lds[row * 64 + 16 + pj]);
            const float gg = tanhf(lds[row * 64 + 32 + pj]);
            const float og = sigf(lds[row * 64 + 48 + pj]);
            const float cn = fg * creg[r] + ig * gg;
            creg[r] = cn;
            const float hn = og * tanhf(cn);
            h32[row * HID + pcol] = hn;
            ho[row * HID + pcol] = (_Float16)hn;
            if (pool == 0) ring[(t & 3) * (BATCH * HID) + row * HID + pcol] = hn;
            else           out[t * (BATCH * HID) + row * HID + pcol] = hn;
            if (t == SEQ - 1) {
                out[OUT_H + pool * (BATCH * HID) + row * HID + pcol] = hn;
                out[OUT_C + pool * (BATCH * HID) + row * HID + pcol] = cn;
            }
        }
        wg_signal(&cntP[t * 6 + 5]);
    }
}

// ---------------- host launch ----------------
extern "C" void kernel_launch(void* const* d_in, const int* in_sizes, int n_in,
                              void* d_out, int out_size, void* d_ws, size_t ws_size,
                              hipStream_t stream) {
    const float* in_seq  = (const float*)d_in[0];
    const float* l1_mogW = (const float*)d_in[1];
    const float* l1_mogb = (const float*)d_in[2];
    const float* l1_Wih  = (const float*)d_in[3];
    const float* l1_Whh  = (const float*)d_in[4];
    const float* l1_bih  = (const float*)d_in[5];
    const float* l1_bhh  = (const float*)d_in[6];
    const float* l2_mogW = (const float*)d_in[7];
    const float* l2_mogb = (const float*)d_in[8];
    const float* l2_Wih  = (const float*)d_in[9];
    const float* l2_Whh  = (const float*)d_in[10];
    const float* l2_bih  = (const float*)d_in[11];
    const float* l2_bhh  = (const float*)d_in[12];

    // zero sync counters + h masters/broadcasts every launch (deterministic replay)
    hipMemsetAsync(d_ws, 0, ZERO_PREFIX, stream);

    prologue_convert<<<256, 256, 0, stream>>>(l1_mogW, l1_Wih, l1_Whh, l1_bih, l1_bhh,
                                              l2_mogW, l2_Wih, l2_Whh, l2_bih, l2_bhh,
                                              (char*)d_ws);

    moglstm_persist<<<64, 256, 0, stream>>>(in_seq, l1_mogb, l2_mogb,
                                            (float*)d_out, (char*)d_ws);
}